// Round 4
// baseline (610.687 us; speedup 1.0000x reference)
//
#include <hip/hip_runtime.h>

#define IN_CH 128
#define HID   64
#define NC    10
#define BSH   9      // bucket shift: 512 nodes/bucket
#define NBLK  256    // partition blocks

__device__ __forceinline__ int lower_bound_i(const int* a, int n, int v) {
    int lo = 0, hi = n;
    while (lo < hi) { int mid = (lo + hi) >> 1; if (a[mid] < v) lo = mid + 1; else hi = mid; }
    return lo;
}

// ---- per-node degree + rowptr ------------------------------------------

__global__ void k_count(const int* __restrict__ dst, int* __restrict__ cnt, int E) {
    int e = blockIdx.x * blockDim.x + threadIdx.x;
    if (e < E) atomicAdd(&cnt[dst[e]], 1);
}

__global__ void k_scan1(const int* __restrict__ cnt, int* __restrict__ excl,
                        int* __restrict__ bsum, int n) {
    __shared__ int s[256];
    int i = blockIdx.x * 256 + threadIdx.x;
    int v = (i < n) ? cnt[i] : 0;
    s[threadIdx.x] = v;
    __syncthreads();
    for (int off = 1; off < 256; off <<= 1) {
        int t = (threadIdx.x >= off) ? s[threadIdx.x - off] : 0;
        __syncthreads();
        s[threadIdx.x] += t;
        __syncthreads();
    }
    if (i < n) excl[i] = s[threadIdx.x] - v;
    if (threadIdx.x == 255) bsum[blockIdx.x] = s[255];
}

__global__ void k_scan2(int* __restrict__ bsum, int nb) {
    __shared__ int s[512];
    int v = (threadIdx.x < nb) ? bsum[threadIdx.x] : 0;
    s[threadIdx.x] = v;
    __syncthreads();
    for (int off = 1; off < 512; off <<= 1) {
        int t = (threadIdx.x >= off) ? s[threadIdx.x - off] : 0;
        __syncthreads();
        s[threadIdx.x] += t;
        __syncthreads();
    }
    if (threadIdx.x < nb) bsum[threadIdx.x] = s[threadIdx.x] - v;
}

__global__ void k_scan3(int* __restrict__ rowptr, const int* __restrict__ bsum,
                        int n, int E) {
    int i = blockIdx.x * 256 + threadIdx.x;
    if (i < n) rowptr[i] = rowptr[i] + bsum[i >> 8];
    if (i == 0) rowptr[n] = E;
}

__global__ void k_dinv(const int* __restrict__ cnt, float* __restrict__ dinv, int n) {
    int i = blockIdx.x * blockDim.x + threadIdx.x;
    if (i < n) dinv[i] = rsqrtf((float)(cnt[i] + 1));  // +1 self loop
}

// ---- edge partition: coalesced CSR build -------------------------------
// Pass A: per-(block,bucket) histogram.

__global__ void k_histA(const int* __restrict__ dst, int* __restrict__ Gh,
                        int E, int nbuck, int chunk) {
    __shared__ int h[256];
    h[threadIdx.x] = 0;
    __syncthreads();
    int base = blockIdx.x * chunk;
    int lim  = min(base + chunk, E);
    for (int e = base + threadIdx.x; e < lim; e += 256)
        atomicAdd(&h[dst[e] >> BSH], 1);
    __syncthreads();
    if (threadIdx.x < nbuck) Gh[threadIdx.x * NBLK + blockIdx.x] = h[threadIdx.x];
}

// Exclusive scan of Gh (bucket-major, nbuck*NBLK entries); also bstart[b].

__global__ void k_scanG(int* __restrict__ Gh, int* __restrict__ bstart,
                        int n, int nbuck, int E) {
    __shared__ int tot[1024];
    int T = 1024;
    int L = (n + T - 1) / T;
    int lo = threadIdx.x * L, hi = min(lo + L, n);
    int s = 0;
    for (int i = lo; i < hi; i++) s += Gh[i];
    tot[threadIdx.x] = s;
    __syncthreads();
    for (int off = 1; off < T; off <<= 1) {
        int t = (threadIdx.x >= off) ? tot[threadIdx.x - off] : 0;
        __syncthreads();
        tot[threadIdx.x] += t;
        __syncthreads();
    }
    int run = tot[threadIdx.x] - s;
    for (int i = lo; i < hi; i++) {
        int v = Gh[i];
        Gh[i] = run;
        if ((i & (NBLK - 1)) == 0) bstart[i / NBLK] = run;
        run += v;
    }
    if (threadIdx.x == 0) bstart[nbuck] = E;
}

// Pass B: scatter (src,dst) into bucket-partitioned order. Per-block writes
// into each bucket are a contiguous run -> L2-coalesced, ~1x amplification.

__global__ void k_partB(const int* __restrict__ src, const int* __restrict__ dst,
                        const int* __restrict__ Gh, int2* __restrict__ packed,
                        int E, int nbuck, int chunk) {
    __shared__ int cur[256];
    if (threadIdx.x < nbuck) cur[threadIdx.x] = Gh[threadIdx.x * NBLK + blockIdx.x];
    __syncthreads();
    int base = blockIdx.x * chunk;
    int lim  = min(base + chunk, E);
    for (int e = base + threadIdx.x; e < lim; e += 256) {
        int d = dst[e], s = src[e];
        int pos = atomicAdd(&cur[d >> BSH], 1);
        packed[pos] = make_int2(s, d);
    }
}

// Pass C: one block per bucket; LDS node cursors; scatter span = bucket's
// contiguous CSR region (~65 KB) -> L2-hot.

__global__ void k_placeC(const int2* __restrict__ packed, const int* __restrict__ bstart,
                         const int* __restrict__ rowptr, const float* __restrict__ dinv,
                         int2* __restrict__ meta, int nn) {
    __shared__ int cur[1 << BSH];
    int b   = blockIdx.x;
    int nb0 = b << BSH;
    int nnb = min(1 << BSH, nn - nb0);
    for (int j = threadIdx.x; j < nnb; j += blockDim.x) cur[j] = rowptr[nb0 + j];
    __syncthreads();
    int lo = bstart[b], hi = bstart[b + 1];
    for (int e = lo + threadIdx.x; e < hi; e += blockDim.x) {
        int2 p = packed[e];
        float w = dinv[p.x] * dinv[p.y];
        int pos = atomicAdd(&cur[p.y - nb0], 1);
        meta[pos] = make_int2(p.x, __float_as_int(w));
    }
}

// ---- Dense X@W: 128 rows/block, 8x4 register tile, K-chunks of 32 -------

template <int K>
__global__ __launch_bounds__(256) void k_gemm(const float* __restrict__ X,
                                              const float* __restrict__ W,
                                              float* __restrict__ H, int n) {
    __shared__ float4 xs4[128][8];
    __shared__ float4 ws4[32][16];
    int tid  = threadIdx.x;
    int row0 = blockIdx.x * 128;
    int cg = tid & 15, rg = tid >> 4;
    float acc[8][4];
#pragma unroll
    for (int r = 0; r < 8; r++)
#pragma unroll
        for (int c = 0; c < 4; c++) acc[r][c] = 0.f;

    for (int k0 = 0; k0 < K; k0 += 32) {
        int sr = tid >> 3, f4 = tid & 7;
#pragma unroll
        for (int i = 0; i < 4; i++) {
            int row  = sr + i * 32;
            int grow = row0 + row;
            float4 v = make_float4(0.f, 0.f, 0.f, 0.f);
            if (grow < n) v = *(const float4*)&X[(size_t)grow * K + k0 + f4 * 4];
            xs4[row][f4 ^ ((row >> 3) & 3)] = v;
        }
        {
            const float4* Wp = (const float4*)&W[(size_t)k0 * 64];
            int j0 = tid, j1 = tid + 256;
            ws4[j0 >> 4][j0 & 15] = Wp[j0];
            ws4[j1 >> 4][j1 & 15] = Wp[j1];
        }
        __syncthreads();
#pragma unroll
        for (int k4 = 0; k4 < 8; k4++) {
            float4 av[8];
#pragma unroll
            for (int r = 0; r < 8; r++) av[r] = xs4[rg * 8 + r][k4 ^ (rg & 3)];
            float4 wv[4];
#pragma unroll
            for (int kk = 0; kk < 4; kk++) wv[kk] = ws4[k4 * 4 + kk][cg];
#pragma unroll
            for (int kk = 0; kk < 4; kk++) {
#pragma unroll
                for (int r = 0; r < 8; r++) {
                    float a = ((const float*)&av[r])[kk];
                    acc[r][0] += a * wv[kk].x;
                    acc[r][1] += a * wv[kk].y;
                    acc[r][2] += a * wv[kk].z;
                    acc[r][3] += a * wv[kk].w;
                }
            }
        }
        __syncthreads();
    }
#pragma unroll
    for (int r = 0; r < 8; r++) {
        int row = row0 + rg * 8 + r;
        if (row < n)
            *(float4*)&H[(size_t)row * 64 + cg * 4] =
                make_float4(acc[r][0], acc[r][1], acc[r][2], acc[r][3]);
    }
}

// ---- CSR gather agg: wave/node, lane=col, branchless 8-deep MLP ---------

__global__ void k_agg(const float* __restrict__ H, const int2* __restrict__ meta,
                      const int* __restrict__ rowptr, const float* __restrict__ dinv,
                      const float* __restrict__ bias, float* __restrict__ out,
                      int n, int do_relu) {
    int wid  = (blockIdx.x * blockDim.x + threadIdx.x) >> 6;
    int lane = threadIdx.x & 63;
    if (wid >= n) return;
    int beg = rowptr[wid], end = rowptr[wid + 1];
    float dv = dinv[wid];
    float a[8];
    a[0] = dv * dv * H[(size_t)wid * 64 + lane];  // self loop
#pragma unroll
    for (int j = 1; j < 8; j++) a[j] = 0.f;
    for (int e = beg; e < end; e += 8) {
        int2 m[8];
#pragma unroll
        for (int j = 0; j < 8; j++) {
            int ej  = e + j;
            int idx = (ej < end) ? ej : beg;   // branchless clamp
            m[j] = meta[idx];
        }
#pragma unroll
        for (int j = 0; j < 8; j++) {
            float wj = (e + j < end) ? __int_as_float(m[j].y) : 0.f;
            a[j] += wj * H[(size_t)m[j].x * 64 + lane];
        }
    }
    float acc = ((a[0] + a[1]) + (a[2] + a[3])) + ((a[4] + a[5]) + (a[6] + a[7]));
    if (bias) acc += bias[lane];
    if (do_relu) acc = fmaxf(acc, 0.f);
    out[(size_t)wid * 64 + lane] = acc;
}

// ---- Mean pool, chunk-parallel ------------------------------------------

__global__ void k_pool(const float* __restrict__ G, const int* __restrict__ batch,
                       float* __restrict__ Psum, int n) {
    int base = blockIdx.x * 256;
    int lane = threadIdx.x & 63, rg = threadIdx.x >> 6;
    int lim = min(base + 256, n);
    int cur = -1;
    float acc = 0.f;
    for (int r = base + rg; r < lim; r += 4) {
        int g = batch[r];
        if (g != cur) {
            if (cur >= 0) atomicAdd(&Psum[cur * 64 + lane], acc);
            cur = g;
            acc = 0.f;
        }
        acc += G[(size_t)r * 64 + lane];
    }
    if (cur >= 0) atomicAdd(&Psum[cur * 64 + lane], acc);
}

// ---- mean + pooled@W3 + b3 + log_softmax --------------------------------

__global__ void k_final(const float* __restrict__ Psum, const int* __restrict__ batch,
                        int n, const float* __restrict__ W3, const float* __restrict__ b3,
                        float* __restrict__ out, int ng) {
    __shared__ float P[64 * 64];
    __shared__ float s[64][NC];
    __shared__ float lse[64];
    __shared__ float invc[64];
    int t = threadIdx.x;
    if (t < ng) {
        int lo = lower_bound_i(batch, n, t);
        int hi = lower_bound_i(batch, n, t + 1);
        invc[t] = 1.f / (float)max(hi - lo, 1);
    }
    __syncthreads();
    for (int i = t; i < ng * 64; i += blockDim.x) P[i] = Psum[i] * invc[i >> 6];
    __syncthreads();
    if (t < ng * NC) {
        int g = t / NC, c = t % NC;
        float acc = b3[c];
        for (int k = 0; k < 64; k++) acc += P[g * 64 + k] * W3[k * NC + c];
        s[g][c] = acc;
    }
    __syncthreads();
    if (t < ng) {
        float m = -1e30f;
        for (int c = 0; c < NC; c++) m = fmaxf(m, s[t][c]);
        float sum = 0.f;
        for (int c = 0; c < NC; c++) sum += expf(s[t][c] - m);
        lse[t] = m + logf(sum);
    }
    __syncthreads();
    if (t < ng * NC) {
        int g = t / NC, c = t % NC;
        out[t] = s[g][c] - lse[g];
    }
}

// ---- launch -------------------------------------------------------------

extern "C" void kernel_launch(void* const* d_in, const int* in_sizes, int n_in,
                              void* d_out, int out_size, void* d_ws, size_t ws_size,
                              hipStream_t stream) {
    const float* x     = (const float*)d_in[0];
    const int*   ei    = (const int*)  d_in[1];
    const int*   batch = (const int*)  d_in[2];
    const float* W1    = (const float*)d_in[3];
    const float* b1    = (const float*)d_in[4];
    const float* W2    = (const float*)d_in[5];
    const float* b2    = (const float*)d_in[6];
    const float* W3    = (const float*)d_in[7];
    const float* b3    = (const float*)d_in[8];
    float*       out   = (float*)d_out;

    const int NN = in_sizes[0] / IN_CH;   // 100000
    const int E  = in_sizes[1] / 2;       // 1600000
    const int NG = out_size / NC;         // 64
    const int nbuck = (NN + (1 << BSH) - 1) >> BSH;  // 196

    const int* src = ei;
    const int* dst = ei + E;

    char* ws = (char*)d_ws;
    size_t off = 0;
    auto carve = [&](size_t bytes) -> char* {
        char* p = ws + off;
        off = (off + bytes + 255) & ~(size_t)255;
        return p;
    };
    int*   cnt    = (int*)  carve((size_t)NN * 4);
    int*   rowptr = (int*)  carve((size_t)(NN + 1) * 4);
    float* dinv   = (float*)carve((size_t)NN * 4);
    int*   bsum   = (int*)  carve(4096);
    int*   bstart = (int*)  carve((size_t)(nbuck + 1) * 4);
    int2*  meta   = (int2*) carve((size_t)E * 8);
    float* bufA   = (float*)carve((size_t)NN * HID * 4);
    float* bufB   = (float*)carve((size_t)NN * HID * 4);
    float* Psum   = (float*)carve((size_t)NG * HID * 4);
    (void)ws_size;

    // scratch aliases (dead until gemm1/agg1):
    int2* packed = (int2*)bufA;              // E * 8 B <= 25.6 MB
    int*  Gh     = (int*)bufB;               // nbuck*NBLK ints

    const int nbN  = (NN + 255) / 256;
    const int nbE  = (E + 255) / 256;
    const int chnk = (E + NBLK - 1) / NBLK;

    hipMemsetAsync(cnt, 0, (size_t)NN * 4, stream);
    hipMemsetAsync(Psum, 0, (size_t)NG * HID * 4, stream);
    k_count<<<nbE, 256, 0, stream>>>(dst, cnt, E);
    k_scan1<<<nbN, 256, 0, stream>>>(cnt, rowptr, bsum, NN);
    k_scan2<<<1, 512, 0, stream>>>(bsum, nbN);
    k_scan3<<<nbN, 256, 0, stream>>>(rowptr, bsum, NN, E);
    k_dinv <<<nbN, 256, 0, stream>>>(cnt, dinv, NN);

    k_histA <<<NBLK, 256, 0, stream>>>(dst, Gh, E, nbuck, chnk);
    k_scanG <<<1, 1024, 0, stream>>>(Gh, bstart, nbuck * NBLK, nbuck, E);
    k_partB <<<NBLK, 256, 0, stream>>>(src, dst, Gh, packed, E, nbuck, chnk);
    k_placeC<<<nbuck, 512, 0, stream>>>(packed, bstart, rowptr, dinv, meta, NN);

    const int nbG = (NN + 127) / 128;
    const int nbA = ((size_t)NN * 64 + 255) / 256;

    k_gemm<IN_CH><<<nbG, 256, 0, stream>>>(x, W1, bufA, NN);
    k_agg<<<nbA, 256, 0, stream>>>(bufA, meta, rowptr, dinv, b1, bufB, NN, 1);
    k_gemm<HID><<<nbG, 256, 0, stream>>>(bufB, W2, bufA, NN);
    k_agg<<<nbA, 256, 0, stream>>>(bufA, meta, rowptr, dinv, b2, bufB, NN, 1);
    k_agg<<<nbA, 256, 0, stream>>>(bufB, meta, rowptr, dinv, nullptr, bufA, NN, 0);
    k_pool<<<nbN, 256, 0, stream>>>(bufA, batch, Psum, NN);
    k_final<<<1, 640, 0, stream>>>(Psum, batch, NN, W3, b3, out, NG);
}

// Round 5
// 491.472 us; speedup vs baseline: 1.2426x; 1.2426x over previous
//
#include <hip/hip_runtime.h>

#define IN_CH 128
#define HID   64
#define NC    10

typedef unsigned short bfu;

static __device__ __forceinline__ bfu bf16_of(float f) {
    unsigned u = __float_as_uint(f);
    unsigned r = (u + 0x7FFF + ((u >> 16) & 1)) >> 16;   // RNE
    return (bfu)r;
}
static __device__ __forceinline__ float f_of_bf16(bfu u) {
    return __uint_as_float(((unsigned)u) << 16);
}

__device__ __forceinline__ int lower_bound_i(const int* a, int n, int v) {
    int lo = 0, hi = n;
    while (lo < hi) { int mid = (lo + hi) >> 1; if (a[mid] < v) lo = mid + 1; else hi = mid; }
    return lo;
}

// ---- per-node degree + rowptr ------------------------------------------

__global__ void k_count(const int* __restrict__ dst, int* __restrict__ cnt, int E) {
    int e = blockIdx.x * blockDim.x + threadIdx.x;
    if (e < E) atomicAdd(&cnt[dst[e]], 1);
}

__global__ void k_scan1(const int* __restrict__ cnt, int* __restrict__ excl,
                        int* __restrict__ bsum, int n) {
    __shared__ int s[256];
    int i = blockIdx.x * 256 + threadIdx.x;
    int v = (i < n) ? cnt[i] : 0;
    s[threadIdx.x] = v;
    __syncthreads();
    for (int off = 1; off < 256; off <<= 1) {
        int t = (threadIdx.x >= off) ? s[threadIdx.x - off] : 0;
        __syncthreads();
        s[threadIdx.x] += t;
        __syncthreads();
    }
    if (i < n) excl[i] = s[threadIdx.x] - v;
    if (threadIdx.x == 255) bsum[blockIdx.x] = s[255];
}

__global__ void k_scan2(int* __restrict__ bsum, int nb) {
    __shared__ int s[512];
    int v = (threadIdx.x < nb) ? bsum[threadIdx.x] : 0;
    s[threadIdx.x] = v;
    __syncthreads();
    for (int off = 1; off < 512; off <<= 1) {
        int t = (threadIdx.x >= off) ? s[threadIdx.x - off] : 0;
        __syncthreads();
        s[threadIdx.x] += t;
        __syncthreads();
    }
    if (threadIdx.x < nb) bsum[threadIdx.x] = s[threadIdx.x] - v;
}

__global__ void k_scan3(int* __restrict__ rowptr, const int* __restrict__ bsum,
                        int* __restrict__ cursor, int n, int E) {
    int i = blockIdx.x * 256 + threadIdx.x;
    if (i < n) {
        int r = rowptr[i] + bsum[i >> 8];
        rowptr[i] = r;
        cursor[i] = r;
    }
    if (i == 0) rowptr[n] = E;
}

__global__ void k_dinv(const int* __restrict__ cnt, float* __restrict__ dinv, int n) {
    int i = blockIdx.x * blockDim.x + threadIdx.x;
    if (i < n) dinv[i] = rsqrtf((float)(cnt[i] + 1));  // +1 self loop
}

// ---- CSR fill, XCD-partitioned by contiguous dst range ------------------
// blockIdx&7 selects a node partition (contiguous 1/8 of nodes -> contiguous
// meta region ~0.8 MB, L2-resident on one XCD under round-robin dispatch).

__global__ void k_fill(const int* __restrict__ src, const int* __restrict__ dst,
                       int* __restrict__ cursor, int* __restrict__ meta,
                       int E, int per) {
    int part  = blockIdx.x & 7;
    int chunk = blockIdx.x >> 3;
    int e = chunk * 256 + threadIdx.x;
    if (e >= E) return;
    int d = dst[e];
    if (d / per != part) return;
    int s = src[e];
    int pos = atomicAdd(&cursor[d], 1);
    meta[pos] = s;
}

// ---- Dense X@W + dinv-scaled bf16 epilogue ------------------------------
// 128 rows/block, 8x4 register tile, K-chunks of 32. IN_BF16 templates the
// staging load type. Output G[row] = bf16(dinv[row] * (X@W)[row]).

template <int K, bool IN_BF16>
__global__ __launch_bounds__(256) void k_gemm(const void* __restrict__ Xv,
                                              const float* __restrict__ W,
                                              const float* __restrict__ dinv,
                                              bfu* __restrict__ G, int n) {
    __shared__ float4 xs4[128][8];
    __shared__ float4 ws4[32][16];
    int tid  = threadIdx.x;
    int row0 = blockIdx.x * 128;
    int cg = tid & 15, rg = tid >> 4;
    float acc[8][4];
#pragma unroll
    for (int r = 0; r < 8; r++)
#pragma unroll
        for (int c = 0; c < 4; c++) acc[r][c] = 0.f;

    for (int k0 = 0; k0 < K; k0 += 32) {
        int sr = tid >> 3, f4 = tid & 7;
#pragma unroll
        for (int i = 0; i < 4; i++) {
            int row  = sr + i * 32;
            int grow = row0 + row;
            float4 v = make_float4(0.f, 0.f, 0.f, 0.f);
            if (grow < n) {
                if (IN_BF16) {
                    const bfu* X = (const bfu*)Xv;
                    ushort4 u = *(const ushort4*)&X[(size_t)grow * K + k0 + f4 * 4];
                    v = make_float4(f_of_bf16(u.x), f_of_bf16(u.y),
                                    f_of_bf16(u.z), f_of_bf16(u.w));
                } else {
                    const float* X = (const float*)Xv;
                    v = *(const float4*)&X[(size_t)grow * K + k0 + f4 * 4];
                }
            }
            xs4[row][f4 ^ ((row >> 3) & 3)] = v;
        }
        {
            const float4* Wp = (const float4*)&W[(size_t)k0 * 64];
            int j0 = tid, j1 = tid + 256;
            ws4[j0 >> 4][j0 & 15] = Wp[j0];
            ws4[j1 >> 4][j1 & 15] = Wp[j1];
        }
        __syncthreads();
#pragma unroll
        for (int k4 = 0; k4 < 8; k4++) {
            float4 av[8];
#pragma unroll
            for (int r = 0; r < 8; r++) av[r] = xs4[rg * 8 + r][k4 ^ (rg & 3)];
            float4 wv[4];
#pragma unroll
            for (int kk = 0; kk < 4; kk++) wv[kk] = ws4[k4 * 4 + kk][cg];
#pragma unroll
            for (int kk = 0; kk < 4; kk++) {
#pragma unroll
                for (int r = 0; r < 8; r++) {
                    float a = ((const float*)&av[r])[kk];
                    acc[r][0] += a * wv[kk].x;
                    acc[r][1] += a * wv[kk].y;
                    acc[r][2] += a * wv[kk].z;
                    acc[r][3] += a * wv[kk].w;
                }
            }
        }
        __syncthreads();
    }
#pragma unroll
    for (int r = 0; r < 8; r++) {
        int row = row0 + rg * 8 + r;
        if (row < n) {
            float dv = dinv[row];
            ushort4 o;
            o.x = bf16_of(acc[r][0] * dv);
            o.y = bf16_of(acc[r][1] * dv);
            o.z = bf16_of(acc[r][2] * dv);
            o.w = bf16_of(acc[r][3] * dv);
            *(ushort4*)&G[(size_t)row * 64 + cg * 4] = o;
        }
    }
}

// ---- CSR gather agg: wave/node, lane=col, branchless 8-deep MLP ---------
// G rows are pre-scaled by dinv (weight folded), bf16. post_scale: multiply
// the (bias/relu'd) result by dinv again so the output is directly the next
// gather buffer.

__global__ void k_agg(const bfu* __restrict__ G, const int* __restrict__ meta,
                      const int* __restrict__ rowptr, const float* __restrict__ dinv,
                      const float* __restrict__ bias, bfu* __restrict__ out,
                      int n, int do_relu, int post_scale) {
    int wid  = (blockIdx.x * blockDim.x + threadIdx.x) >> 6;
    int lane = threadIdx.x & 63;
    if (wid >= n) return;
    int beg = rowptr[wid], end = rowptr[wid + 1];
    float a[8];
    a[0] = f_of_bf16(G[(size_t)wid * 64 + lane]);  // self loop (pre-scaled)
#pragma unroll
    for (int j = 1; j < 8; j++) a[j] = 0.f;
    for (int e = beg; e < end; e += 8) {
        int m[8];
#pragma unroll
        for (int j = 0; j < 8; j++) {
            int ej  = e + j;
            int idx = (ej < end) ? ej : beg;   // branchless clamp
            m[j] = meta[idx];
        }
#pragma unroll
        for (int j = 0; j < 8; j++) {
            float v = f_of_bf16(G[(size_t)m[j] * 64 + lane]);
            a[j] += (e + j < end) ? v : 0.f;
        }
    }
    float acc = ((a[0] + a[1]) + (a[2] + a[3])) + ((a[4] + a[5]) + (a[6] + a[7]));
    float dv = dinv[wid];
    acc *= dv;
    if (bias) acc += bias[lane];
    if (do_relu) acc = fmaxf(acc, 0.f);
    if (post_scale) acc *= dv;
    out[(size_t)wid * 64 + lane] = bf16_of(acc);
}

// ---- Mean pool, chunk-parallel (bf16 input, fp32 accum) -----------------

__global__ void k_pool(const bfu* __restrict__ G, const int* __restrict__ batch,
                       float* __restrict__ Psum, int n) {
    int base = blockIdx.x * 256;
    int lane = threadIdx.x & 63, rg = threadIdx.x >> 6;
    int lim = min(base + 256, n);
    int cur = -1;
    float acc = 0.f;
    for (int r = base + rg; r < lim; r += 4) {
        int g = batch[r];
        if (g != cur) {
            if (cur >= 0) atomicAdd(&Psum[cur * 64 + lane], acc);
            cur = g;
            acc = 0.f;
        }
        acc += f_of_bf16(G[(size_t)r * 64 + lane]);
    }
    if (cur >= 0) atomicAdd(&Psum[cur * 64 + lane], acc);
}

// ---- mean + pooled@W3 + b3 + log_softmax --------------------------------

__global__ void k_final(const float* __restrict__ Psum, const int* __restrict__ batch,
                        int n, const float* __restrict__ W3, const float* __restrict__ b3,
                        float* __restrict__ out, int ng) {
    __shared__ float P[64 * 64];
    __shared__ float s[64][NC];
    __shared__ float lse[64];
    __shared__ float invc[64];
    int t = threadIdx.x;
    if (t < ng) {
        int lo = lower_bound_i(batch, n, t);
        int hi = lower_bound_i(batch, n, t + 1);
        invc[t] = 1.f / (float)max(hi - lo, 1);
    }
    __syncthreads();
    for (int i = t; i < ng * 64; i += blockDim.x) P[i] = Psum[i] * invc[i >> 6];
    __syncthreads();
    if (t < ng * NC) {
        int g = t / NC, c = t % NC;
        float acc = b3[c];
        for (int k = 0; k < 64; k++) acc += P[g * 64 + k] * W3[k * NC + c];
        s[g][c] = acc;
    }
    __syncthreads();
    if (t < ng) {
        float m = -1e30f;
        for (int c = 0; c < NC; c++) m = fmaxf(m, s[t][c]);
        float sum = 0.f;
        for (int c = 0; c < NC; c++) sum += expf(s[t][c] - m);
        lse[t] = m + logf(sum);
    }
    __syncthreads();
    if (t < ng * NC) {
        int g = t / NC, c = t % NC;
        out[t] = s[g][c] - lse[g];
    }
}

// ---- launch -------------------------------------------------------------

extern "C" void kernel_launch(void* const* d_in, const int* in_sizes, int n_in,
                              void* d_out, int out_size, void* d_ws, size_t ws_size,
                              hipStream_t stream) {
    const float* x     = (const float*)d_in[0];
    const int*   ei    = (const int*)  d_in[1];
    const int*   batch = (const int*)  d_in[2];
    const float* W1    = (const float*)d_in[3];
    const float* b1    = (const float*)d_in[4];
    const float* W2    = (const float*)d_in[5];
    const float* b2    = (const float*)d_in[6];
    const float* W3    = (const float*)d_in[7];
    const float* b3    = (const float*)d_in[8];
    float*       out   = (float*)d_out;

    const int NN = in_sizes[0] / IN_CH;   // 100000
    const int E  = in_sizes[1] / 2;       // 1600000
    const int NG = out_size / NC;         // 64

    const int* src = ei;
    const int* dst = ei + E;

    char* ws = (char*)d_ws;
    size_t off = 0;
    auto carve = [&](size_t bytes) -> char* {
        char* p = ws + off;
        off = (off + bytes + 255) & ~(size_t)255;
        return p;
    };
    int*   cnt    = (int*)  carve((size_t)NN * 4);
    int*   rowptr = (int*)  carve((size_t)(NN + 1) * 4);
    int*   cursor = (int*)  carve((size_t)NN * 4);
    float* dinv   = (float*)carve((size_t)NN * 4);
    int*   bsum   = (int*)  carve(4096);
    int*   meta   = (int*)  carve((size_t)E * 4);
    bfu*   bufA   = (bfu*)  carve((size_t)NN * HID * 2);
    bfu*   bufB   = (bfu*)  carve((size_t)NN * HID * 2);
    float* Psum   = (float*)carve((size_t)NG * HID * 4);
    (void)ws_size;

    const int nbN = (NN + 255) / 256;
    const int nbE = (E + 255) / 256;
    const int per = (NN + 7) / 8;

    hipMemsetAsync(cnt, 0, (size_t)NN * 4, stream);
    hipMemsetAsync(Psum, 0, (size_t)NG * HID * 4, stream);
    k_count<<<nbE, 256, 0, stream>>>(dst, cnt, E);
    k_scan1<<<nbN, 256, 0, stream>>>(cnt, rowptr, bsum, NN);
    k_scan2<<<1, 512, 0, stream>>>(bsum, nbN);
    k_scan3<<<nbN, 256, 0, stream>>>(rowptr, bsum, cursor, NN, E);
    k_dinv <<<nbN, 256, 0, stream>>>(cnt, dinv, NN);
    k_fill <<<nbE * 8, 256, 0, stream>>>(src, dst, cursor, meta, E, per);

    const int nbG = (NN + 127) / 128;
    const int nbA = ((size_t)NN * 64 + 255) / 256;

    // layer 1: G1 = dinv*(x@W1) ; H1 = relu(dinv*(G1[v]+sum G1[src]) + b1)
    k_gemm<IN_CH, false><<<nbG, 256, 0, stream>>>(x, W1, dinv, bufA, NN);
    k_agg<<<nbA, 256, 0, stream>>>(bufA, meta, rowptr, dinv, b1, bufB, NN, 1, 0);
    // layer 2: G2 = dinv*(H1@W2) ; G3 = dinv*relu(dinv*(...)+b2)
    k_gemm<HID, true><<<nbG, 256, 0, stream>>>(bufB, W2, dinv, bufA, NN);
    k_agg<<<nbA, 256, 0, stream>>>(bufA, meta, rowptr, dinv, b2, bufB, NN, 1, 1);
    // layer 3 (reordered): p = dinv*(G3[v]+sum G3[src]) ; pool ; @W3 ; lsm
    k_agg<<<nbA, 256, 0, stream>>>(bufB, meta, rowptr, dinv, nullptr, bufA, NN, 0, 0);
    k_pool<<<nbN, 256, 0, stream>>>(bufA, batch, Psum, NN);
    k_final<<<1, 640, 0, stream>>>(Psum, batch, NN, W3, b3, out, NG);
}